// Round 1
// baseline (396.952 us; speedup 1.0000x reference)
//
#include <hip/hip_runtime.h>

#define D_MODEL 1024
#define SEQ 2048
#define BATCH 4
#define HEADS 16
#define HDIM 64

typedef short bf16x8 __attribute__((ext_vector_type(8)));
typedef float f32x4 __attribute__((ext_vector_type(4)));

__device__ __forceinline__ unsigned short f2bf(float f) {
  union { float f; unsigned int u; } c; c.f = f;
  unsigned int u = c.u;
  unsigned int r = (u + 0x7FFFu + ((u >> 16) & 1u)) >> 16;
  return (unsigned short)r;
}

__device__ __forceinline__ void async16(const void* g, const void* lds) {
  __builtin_amdgcn_global_load_lds((const __attribute__((address_space(1))) void*)g,
                                   (__attribute__((address_space(3))) void*)lds, 16, 0, 0);
}

// ---------------------------------------------------------------- convert
__global__ void cvt_kernel(const float* __restrict__ src,
                           unsigned short* __restrict__ dst, int n4) {
  int i = blockIdx.x * 256 + threadIdx.x;
  if (i >= n4) return;
  float4 v = ((const float4*)src)[i];
  ushort4 o;
  o.x = f2bf(v.x); o.y = f2bf(v.y); o.z = f2bf(v.z); o.w = f2bf(v.w);
  ((ushort4*)dst)[i] = o;
}

// ---------------------------------------------------------------- GEMM  C = A * B^T
// A: [M][1024] bf16 row-major, Bw: [N][1024] bf16 row-major (N rows = output channels)
// MODE 0: N=3072 (Wq|Wk|Wv), scatter bf16 to Q/K/V [B*H][S][Dh]
// MODE 1: N=1024 (Wo), write fp32 out [M][1024]
template <int MODE>
__global__ __launch_bounds__(256, 2) void gemm_bt(
    const unsigned short* __restrict__ A, const unsigned short* __restrict__ Bw,
    unsigned short* __restrict__ Qd, unsigned short* __restrict__ Kd,
    unsigned short* __restrict__ Vd, float* __restrict__ Od) {
  __shared__ unsigned short At[128 * 32];
  __shared__ unsigned short Bt[128 * 32];
  const int t = threadIdx.x;
  const int lane = t & 63;
  const int wid = t >> 6;
  const int wr = wid >> 1;
  const int wc = wid & 1;
  const int m0 = blockIdx.y * 128;
  const int n0 = blockIdx.x * 128;
  const int K = 1024;
  f32x4 acc[4][4] = {};

  const int srow = t >> 2;          // 0..63
  const int skk = (t & 3) << 3;     // 0,8,16,24
  const unsigned short* Ap = A + (size_t)(m0 + srow) * K + skk;
  const unsigned short* Bp = Bw + (size_t)(n0 + srow) * K + skk;
  const int lrow = lane & 15;
  const int lk = (lane >> 4) << 3;

  for (int kt = 0; kt < K; kt += 32) {
    __syncthreads();
    async16(Ap + kt, &At[t * 8]);
    async16(Ap + kt + 64 * K, &At[2048 + t * 8]);
    async16(Bp + kt, &Bt[t * 8]);
    async16(Bp + kt + 64 * K, &Bt[2048 + t * 8]);
    asm volatile("s_waitcnt vmcnt(0)" ::: "memory");
    __syncthreads();
    bf16x8 af[4], bfr[4];
#pragma unroll
    for (int f = 0; f < 4; ++f) {
      af[f] = *(const bf16x8*)&At[(wr * 64 + f * 16 + lrow) * 32 + lk];
      bfr[f] = *(const bf16x8*)&Bt[(wc * 64 + f * 16 + lrow) * 32 + lk];
    }
#pragma unroll
    for (int fm = 0; fm < 4; ++fm)
#pragma unroll
      for (int fn = 0; fn < 4; ++fn)
        acc[fm][fn] = __builtin_amdgcn_mfma_f32_16x16x32_bf16(af[fm], bfr[fn],
                                                              acc[fm][fn], 0, 0, 0);
  }

#pragma unroll
  for (int fm = 0; fm < 4; ++fm) {
#pragma unroll
    for (int fn = 0; fn < 4; ++fn) {
#pragma unroll
      for (int r = 0; r < 4; ++r) {
        int m = m0 + wr * 64 + fm * 16 + (lane >> 4) * 4 + r;
        int n = n0 + wc * 64 + fn * 16 + (lane & 15);
        float v = acc[fm][fn][r];
        if (MODE == 0) {
          int p = n >> 10;
          int h = (n >> 6) & 15;
          int dh = n & 63;
          int b = m >> 11;
          int s = m & 2047;
          unsigned short* dst = (p == 0) ? Qd : ((p == 1) ? Kd : Vd);
          dst[(((size_t)(b * HEADS + h)) * SEQ + s) * HDIM + dh] = f2bf(v);
        } else {
          Od[(size_t)m * D_MODEL + n] = v;
        }
      }
    }
  }
}

// ---------------------------------------------------------------- flash attention (causal)
// Q,K,V: [B*H][S][Dh] bf16.  Out ctx: [B*S][D_MODEL] bf16.
__global__ __launch_bounds__(256, 2) void attn_fwd(
    const unsigned short* __restrict__ Qg, const unsigned short* __restrict__ Kg,
    const unsigned short* __restrict__ Vg, unsigned short* __restrict__ Cg) {
  __shared__ unsigned short Kl[64 * 72];      // [key][dh] +8 pad
  __shared__ unsigned short Vt[64 * 72];      // [dh][key] +8 pad (transposed)
  __shared__ unsigned short Pl[4][32 * 72];   // per-wave P tile [qrow][key] +8 pad

  const int t = threadIdx.x;
  const int lane = t & 63;
  const int wq = t >> 6;
  const int q0 = blockIdx.x * 128;
  const int bh = blockIdx.y;
  const size_t base = (size_t)bh * SEQ * HDIM;
  const unsigned short* Qb = Qg + base;
  const unsigned short* Kb = Kg + base;
  const unsigned short* Vb = Vg + base;

  const int l15 = lane & 15;
  const int lh = lane >> 4;  // 0..3
  const int qrow = q0 + wq * 32;

  bf16x8 qf[2][2];
#pragma unroll
  for (int fm = 0; fm < 2; ++fm)
#pragma unroll
    for (int ks = 0; ks < 2; ++ks)
      qf[fm][ks] = *(const bf16x8*)&Qb[(size_t)(qrow + fm * 16 + l15) * HDIM +
                                       ks * 32 + lh * 8];

  f32x4 acc[2][4] = {};
  float mrun[2][4], lrun[2][4];
#pragma unroll
  for (int fm = 0; fm < 2; ++fm)
#pragma unroll
    for (int r = 0; r < 4; ++r) { mrun[fm][r] = -1e30f; lrun[fm][r] = 0.f; }

  const int kv_end = q0 + 128;
  for (int kv0 = 0; kv0 < kv_end; kv0 += 64) {
    __syncthreads();
#pragma unroll
    for (int it = 0; it < 2; ++it) {
      int li = it * 256 + t;
      int key = li >> 3;
      int dh0 = (li & 7) << 3;
      int4 kv = *(const int4*)&Kb[(size_t)(kv0 + key) * HDIM + dh0];
      *(int4*)&Kl[key * 72 + dh0] = kv;
      int4 vv = *(const int4*)&Vb[(size_t)(kv0 + key) * HDIM + dh0];
      const unsigned short* vs = (const unsigned short*)&vv;
#pragma unroll
      for (int j = 0; j < 8; ++j) Vt[(dh0 + j) * 72 + key] = vs[j];
    }
    __syncthreads();

    // S = Q K^T  (per wave: 32 q-rows x 64 keys)
    f32x4 sfr[2][4] = {};
#pragma unroll
    for (int ks = 0; ks < 2; ++ks) {
      bf16x8 kf[4];
#pragma unroll
      for (int fn = 0; fn < 4; ++fn)
        kf[fn] = *(const bf16x8*)&Kl[(fn * 16 + l15) * 72 + ks * 32 + lh * 8];
#pragma unroll
      for (int fm = 0; fm < 2; ++fm)
#pragma unroll
        for (int fn = 0; fn < 4; ++fn)
          sfr[fm][fn] = __builtin_amdgcn_mfma_f32_16x16x32_bf16(
              qf[fm][ks], kf[fn], sfr[fm][fn], 0, 0, 0);
    }

    const bool need_mask = (kv0 + 63) > qrow;  // wave-uniform
    float corr[2][4];
#pragma unroll
    for (int fm = 0; fm < 2; ++fm) {
#pragma unroll
      for (int r = 0; r < 4; ++r) {
        int row = qrow + fm * 16 + lh * 4 + r;
        float v0 = sfr[fm][0][r] * 0.125f;
        float v1 = sfr[fm][1][r] * 0.125f;
        float v2 = sfr[fm][2][r] * 0.125f;
        float v3 = sfr[fm][3][r] * 0.125f;
        if (need_mask) {
          if (kv0 + 0 + l15 > row) v0 = -1e30f;
          if (kv0 + 16 + l15 > row) v1 = -1e30f;
          if (kv0 + 32 + l15 > row) v2 = -1e30f;
          if (kv0 + 48 + l15 > row) v3 = -1e30f;
        }
        float tm = fmaxf(fmaxf(v0, v1), fmaxf(v2, v3));
#pragma unroll
        for (int m = 1; m < 16; m <<= 1) tm = fmaxf(tm, __shfl_xor(tm, m));
        float mnew = fmaxf(mrun[fm][r], tm);
        float c = __expf(mrun[fm][r] - mnew);
        float p0 = __expf(v0 - mnew);
        float p1 = __expf(v1 - mnew);
        float p2 = __expf(v2 - mnew);
        float p3 = __expf(v3 - mnew);
        float ps = p0 + p1 + p2 + p3;
#pragma unroll
        for (int m = 1; m < 16; m <<= 1) ps += __shfl_xor(ps, m);
        lrun[fm][r] = lrun[fm][r] * c + ps;
        mrun[fm][r] = mnew;
        corr[fm][r] = c;
        int prow = fm * 16 + lh * 4 + r;
        Pl[wq][prow * 72 + 0 + l15] = f2bf(p0);
        Pl[wq][prow * 72 + 16 + l15] = f2bf(p1);
        Pl[wq][prow * 72 + 32 + l15] = f2bf(p2);
        Pl[wq][prow * 72 + 48 + l15] = f2bf(p3);
      }
    }
#pragma unroll
    for (int fm = 0; fm < 2; ++fm)
#pragma unroll
      for (int fn = 0; fn < 4; ++fn)
#pragma unroll
        for (int r = 0; r < 4; ++r) acc[fm][fn][r] *= corr[fm][r];

    // ctx += P V
#pragma unroll
    for (int ks = 0; ks < 2; ++ks) {
      bf16x8 pf[2], vf[4];
#pragma unroll
      for (int fm = 0; fm < 2; ++fm)
        pf[fm] = *(const bf16x8*)&Pl[wq][(fm * 16 + l15) * 72 + ks * 32 + lh * 8];
#pragma unroll
      for (int fn = 0; fn < 4; ++fn)
        vf[fn] = *(const bf16x8*)&Vt[(fn * 16 + l15) * 72 + ks * 32 + lh * 8];
#pragma unroll
      for (int fm = 0; fm < 2; ++fm)
#pragma unroll
        for (int fn = 0; fn < 4; ++fn)
          acc[fm][fn] = __builtin_amdgcn_mfma_f32_16x16x32_bf16(pf[fm], vf[fn],
                                                                acc[fm][fn], 0, 0, 0);
    }
  }

  const int b = bh >> 4;
  const int h = bh & 15;
#pragma unroll
  for (int fm = 0; fm < 2; ++fm) {
#pragma unroll
    for (int r = 0; r < 4; ++r) {
      int s = qrow + fm * 16 + lh * 4 + r;
      float inv = 1.0f / lrun[fm][r];
#pragma unroll
      for (int fn = 0; fn < 4; ++fn) {
        int dh = fn * 16 + l15;
        Cg[((size_t)(b * SEQ + s)) * D_MODEL + h * HDIM + dh] =
            f2bf(acc[fm][fn][r] * inv);
      }
    }
  }
}

// ---------------------------------------------------------------- launch
extern "C" void kernel_launch(void* const* d_in, const int* in_sizes, int n_in,
                              void* d_out, int out_size, void* d_ws, size_t ws_size,
                              hipStream_t stream) {
  const float* x = (const float*)d_in[0];
  const float* Wq = (const float*)d_in[1];
  const float* Wk = (const float*)d_in[2];
  const float* Wv = (const float*)d_in[3];
  const float* Wo = (const float*)d_in[4];
  float* out = (float*)d_out;

  char* ws = (char*)d_ws;
  unsigned short* xb   = (unsigned short*)(ws);                    // 16 MB
  unsigned short* Wqkv = (unsigned short*)(ws + (16u << 20));      // 6 MB
  unsigned short* Wob  = (unsigned short*)(ws + (22u << 20));      // 2 MB
  unsigned short* Qb   = (unsigned short*)(ws + (24u << 20));      // 16 MB
  unsigned short* Kb   = (unsigned short*)(ws + (40u << 20));      // 16 MB
  unsigned short* Vb   = (unsigned short*)(ws + (56u << 20));      // 16 MB
  unsigned short* Cb   = (unsigned short*)(ws + (72u << 20));      // 16 MB

  const int W4 = (D_MODEL * D_MODEL) / 4;
  cvt_kernel<<<dim3(8192), dim3(256), 0, stream>>>(x, xb, (BATCH * SEQ * D_MODEL) / 4);
  cvt_kernel<<<dim3(1024), dim3(256), 0, stream>>>(Wq, Wqkv, W4);
  cvt_kernel<<<dim3(1024), dim3(256), 0, stream>>>(Wk, Wqkv + D_MODEL * D_MODEL, W4);
  cvt_kernel<<<dim3(1024), dim3(256), 0, stream>>>(Wv, Wqkv + 2 * D_MODEL * D_MODEL, W4);
  cvt_kernel<<<dim3(1024), dim3(256), 0, stream>>>(Wo, Wob, W4);

  gemm_bt<0><<<dim3(24, 64), dim3(256), 0, stream>>>(xb, Wqkv, Qb, Kb, Vb, nullptr);
  attn_fwd<<<dim3(16, 64), dim3(256), 0, stream>>>(Qb, Kb, Vb, Cb);
  gemm_bt<1><<<dim3(8, 64), dim3(256), 0, stream>>>(Cb, Wob, nullptr, nullptr, nullptr, out);
}

// Round 2
// 188.602 us; speedup vs baseline: 2.1047x; 2.1047x over previous
//
#include <hip/hip_runtime.h>

#define D_MODEL 1024
#define SEQ 2048
#define BATCH 4
#define HEADS 16
#define HDIM 64

typedef short bf16x8 __attribute__((ext_vector_type(8)));
typedef float f32x4 __attribute__((ext_vector_type(4)));

__device__ __forceinline__ unsigned short f2bf(float f) {
  union { float f; unsigned int u; } c; c.f = f;
  unsigned int u = c.u;
  unsigned int r = (u + 0x7FFFu + ((u >> 16) & 1u)) >> 16;
  return (unsigned short)r;
}

__device__ __forceinline__ unsigned int cvt_pk_bf16(float a, float b) {
  unsigned int r;
  asm("v_cvt_pk_bf16_f32 %0, %1, %2" : "=v"(r) : "v"(a), "v"(b));
  return r;
}

__device__ __forceinline__ void async16(const void* g, const void* lds) {
  __builtin_amdgcn_global_load_lds((const __attribute__((address_space(1))) void*)g,
                                   (__attribute__((address_space(3))) void*)lds, 16, 0, 0);
}

// ---------------------------------------------------------------- convert
__global__ void cvt_kernel(const float* __restrict__ src,
                           unsigned short* __restrict__ dst, int n4) {
  int i = blockIdx.x * 256 + threadIdx.x;
  if (i >= n4) return;
  float4 v = ((const float4*)src)[i];
  ushort4 o;
  o.x = f2bf(v.x); o.y = f2bf(v.y); o.z = f2bf(v.z); o.w = f2bf(v.w);
  ((ushort4*)dst)[i] = o;
}

// ---------------------------------------------------------------- GEMM  C = A * B^T
// A: [M][1024] bf16 row-major, Bw: [N][1024] bf16 row-major.
// MODE 0: N in [0,2048) of Wqkv -> scatter bf16 to Q/K [B*H][S][Dh]
// MODE 1: N=1024 (Wo) -> fp32 out [M][1024]
// MODE 2: N in [2048,3072) (Wv) -> SWAPPED mfma, scatter V^T [B*H][Dh][S]
template <int MODE>
__global__ __launch_bounds__(256, 2) void gemm_bt(
    const unsigned short* __restrict__ A, const unsigned short* __restrict__ Bw,
    unsigned short* __restrict__ Qd, unsigned short* __restrict__ Kd,
    unsigned short* __restrict__ Vtd, float* __restrict__ Od) {
  __shared__ unsigned short At[128 * 32];
  __shared__ unsigned short Bt[128 * 32];
  const int t = threadIdx.x;
  const int lane = t & 63;
  const int wid = t >> 6;
  const int wr = wid >> 1;
  const int wc = wid & 1;
  const int m0 = blockIdx.y * 128;
  const int n0 = (MODE == 2 ? 2048 : 0) + blockIdx.x * 128;
  const int K = 1024;
  f32x4 acc[4][4] = {};

  const int srow = t >> 2;          // 0..63
  const int skk = (t & 3) << 3;     // 0,8,16,24
  const unsigned short* Ap = A + (size_t)(m0 + srow) * K + skk;
  const unsigned short* Bp = Bw + (size_t)(n0 + srow) * K + skk;
  const int lrow = lane & 15;
  const int lk = (lane >> 4) << 3;

  for (int kt = 0; kt < K; kt += 32) {
    __syncthreads();
    async16(Ap + kt, &At[t * 8]);
    async16(Ap + kt + 64 * K, &At[2048 + t * 8]);
    async16(Bp + kt, &Bt[t * 8]);
    async16(Bp + kt + 64 * K, &Bt[2048 + t * 8]);
    asm volatile("s_waitcnt vmcnt(0)" ::: "memory");
    __syncthreads();
    bf16x8 af[4], bfr[4];
#pragma unroll
    for (int f = 0; f < 4; ++f) {
      af[f] = *(const bf16x8*)&At[(wr * 64 + f * 16 + lrow) * 32 + lk];
      bfr[f] = *(const bf16x8*)&Bt[(wc * 64 + f * 16 + lrow) * 32 + lk];
    }
#pragma unroll
    for (int fm = 0; fm < 4; ++fm)
#pragma unroll
      for (int fn = 0; fn < 4; ++fn) {
        if (MODE == 2)
          acc[fm][fn] = __builtin_amdgcn_mfma_f32_16x16x32_bf16(bfr[fn], af[fm],
                                                                acc[fm][fn], 0, 0, 0);
        else
          acc[fm][fn] = __builtin_amdgcn_mfma_f32_16x16x32_bf16(af[fm], bfr[fn],
                                                                acc[fm][fn], 0, 0, 0);
      }
  }

#pragma unroll
  for (int fm = 0; fm < 4; ++fm) {
#pragma unroll
    for (int fn = 0; fn < 4; ++fn) {
#pragma unroll
      for (int r = 0; r < 4; ++r) {
        float v = acc[fm][fn][r];
        if (MODE == 2) {
          // C^T layout: row = n-sub (lh*4+r), col = m (l15)
          int n = n0 + wc * 64 + fn * 16 + (lane >> 4) * 4 + r;
          int m = m0 + wr * 64 + fm * 16 + (lane & 15);
          int h = (n >> 6) & 15;
          int d = n & 63;
          int b = m >> 11;
          int s = m & 2047;
          Vtd[(((size_t)(b * HEADS + h)) * HDIM + d) * SEQ + s] = f2bf(v);
        } else {
          int m = m0 + wr * 64 + fm * 16 + (lane >> 4) * 4 + r;
          int n = n0 + wc * 64 + fn * 16 + (lane & 15);
          if (MODE == 0) {
            int p = n >> 10;  // 0=Q, 1=K
            int h = (n >> 6) & 15;
            int dh = n & 63;
            int b = m >> 11;
            int s = m & 2047;
            unsigned short* dst = (p == 0) ? Qd : Kd;
            dst[(((size_t)(b * HEADS + h)) * SEQ + s) * HDIM + dh] = f2bf(v);
          } else {
            Od[(size_t)m * D_MODEL + n] = v;
          }
        }
      }
    }
  }
}

// ---------------------------------------------------------------- flash attention (causal)
// Q,K: [B*H][S][Dh] bf16.  Vt: [B*H][Dh][S] bf16.  Out ctx: [B*S][D_MODEL] bf16.
// Swapped QK^T (S^T in regs -> in-register softmax), packed-b32 P via LDS,
// XOR-swizzled K/V tiles staged with pre-swizzled global_load_lds sources.
__global__ __launch_bounds__(256, 3) void attn_fwd(
    const unsigned short* __restrict__ Qg, const unsigned short* __restrict__ Kg,
    const unsigned short* __restrict__ Vtg, unsigned short* __restrict__ Cg) {
  __shared__ unsigned short Kl[64 * 64];      // [key][dh], rows XOR-swizzled
  __shared__ unsigned short Vl[64 * 64];      // [dh][key], rows XOR-swizzled
  __shared__ unsigned short Pl[4][32 * 72];   // per-wave P [q][key] +8 pad
  char* KlB = (char*)Kl;
  char* VlB = (char*)Vl;

  const int t = threadIdx.x;
  const int lane = t & 63;
  const int wq = t >> 6;
  const int bh = blockIdx.x;
  const int q0 = (15 - blockIdx.y) * 128;  // heavy blocks first
  const size_t base = (size_t)bh * SEQ * HDIM;
  const unsigned short* Qb = Qg + base;
  const unsigned short* Kb = Kg + base;
  const unsigned short* Vb = Vtg + base;  // [Dh][S]
  char* PlB = (char*)&Pl[wq][0];

  const int l15 = lane & 15;
  const int lh = lane >> 4;  // 0..3
  const int qrow = q0 + wq * 32;

  bf16x8 qf[2][2];
#pragma unroll
  for (int fm = 0; fm < 2; ++fm)
#pragma unroll
    for (int ks = 0; ks < 2; ++ks)
      qf[fm][ks] = *(const bf16x8*)&Qb[(size_t)(qrow + fm * 16 + l15) * HDIM +
                                       ks * 32 + lh * 8];

  f32x4 acc[2][4] = {};
  float mrun[2] = {-1e30f, -1e30f};
  float lrun[2] = {0.f, 0.f};

  // staging: dest byte p = t*16 (+4096). row = p>>7, stored col-byte = (p&127)^((row&7)<<4)
  const int srow = t >> 3;                         // 0..31
  const int sc8 = ((t & 7) ^ (srow & 7)) << 3;     // element offset within row

  const int kv_end = q0 + 128;
  for (int kv0 = 0; kv0 < kv_end; kv0 += 64) {
    __syncthreads();
    async16(Kb + (size_t)(kv0 + srow) * HDIM + sc8, &Kl[t * 8]);
    async16(Kb + (size_t)(kv0 + 32 + srow) * HDIM + sc8, &Kl[2048 + t * 8]);
    async16(Vb + (size_t)srow * SEQ + kv0 + sc8, &Vl[t * 8]);
    async16(Vb + (size_t)(32 + srow) * SEQ + kv0 + sc8, &Vl[2048 + t * 8]);
    asm volatile("s_waitcnt vmcnt(0)" ::: "memory");
    __syncthreads();

    if (kv0 <= qrow + 31) {
      // ---- S^T = K Q^T : C[key][q], lane holds 16 keys for q = l15
      f32x4 sfr[2][4] = {};
#pragma unroll
      for (int ks = 0; ks < 2; ++ks) {
        bf16x8 kf[4];
#pragma unroll
        for (int fn = 0; fn < 4; ++fn) {
          int row = fn * 16 + l15;
          kf[fn] = *(const bf16x8*)&KlB[row * 128 +
                                        ((ks * 64 + lh * 16) ^ ((row & 7) << 4))];
        }
#pragma unroll
        for (int fm = 0; fm < 2; ++fm)
#pragma unroll
          for (int fn = 0; fn < 4; ++fn)
            sfr[fm][fn] = __builtin_amdgcn_mfma_f32_16x16x32_bf16(
                kf[fn], qf[fm][ks], sfr[fm][fn], 0, 0, 0);
      }

      const bool need_mask = (kv0 + 63) > qrow;
#pragma unroll
      for (int fm = 0; fm < 2; ++fm) {
        const int q = qrow + fm * 16 + l15;
        float p[4][4];
        float mt = -1e30f;
#pragma unroll
        for (int fn = 0; fn < 4; ++fn)
#pragma unroll
          for (int r = 0; r < 4; ++r) {
            float v = sfr[fm][fn][r] * 0.125f;
            if (need_mask) {
              int key = kv0 + fn * 16 + lh * 4 + r;
              v = (key <= q) ? v : -1e30f;
            }
            p[fn][r] = v;
            mt = fmaxf(mt, v);
          }
        mt = fmaxf(mt, __shfl_xor(mt, 16));
        mt = fmaxf(mt, __shfl_xor(mt, 32));
        float mnew = fmaxf(mrun[fm], mt);
        float c = __expf(mrun[fm] - mnew);
        mrun[fm] = mnew;
        float st = 0.f;
#pragma unroll
        for (int fn = 0; fn < 4; ++fn)
#pragma unroll
          for (int r = 0; r < 4; ++r) {
            p[fn][r] = __expf(p[fn][r] - mnew);
            st += p[fn][r];
          }
        st += __shfl_xor(st, 16);
        st += __shfl_xor(st, 32);
        lrun[fm] = lrun[fm] * c + st;

        // packed P writes: [q=fm*16+l15][key], b32 (2 keys) each
#pragma unroll
        for (int fn = 0; fn < 4; ++fn) {
#pragma unroll
          for (int w = 0; w < 2; ++w) {
            unsigned int pk = cvt_pk_bf16(p[fn][2 * w], p[fn][2 * w + 1]);
            *(unsigned int*)&PlB[(fm * 16 + l15) * 144 + fn * 32 + lh * 8 + w * 4] = pk;
          }
        }
        // rescale accumulator rows (acc row q = fm*16 + lh*4 + r)
        float cr[4];
#pragma unroll
        for (int r = 0; r < 4; ++r) cr[r] = __shfl(c, lh * 4 + r);
#pragma unroll
        for (int fn = 0; fn < 4; ++fn)
#pragma unroll
          for (int r = 0; r < 4; ++r) acc[fm][fn][r] *= cr[r];
      }

      // ---- ctx += P V
#pragma unroll
      for (int ks = 0; ks < 2; ++ks) {
        bf16x8 pf[2], vf[4];
#pragma unroll
        for (int fm = 0; fm < 2; ++fm)
          pf[fm] = *(const bf16x8*)&PlB[(fm * 16 + l15) * 144 + ks * 64 + lh * 16];
#pragma unroll
        for (int fn = 0; fn < 4; ++fn) {
          int row = fn * 16 + l15;
          vf[fn] = *(const bf16x8*)&VlB[row * 128 +
                                        ((ks * 64 + lh * 16) ^ ((row & 7) << 4))];
        }
#pragma unroll
        for (int fm = 0; fm < 2; ++fm)
#pragma unroll
          for (int fn = 0; fn < 4; ++fn)
            acc[fm][fn] = __builtin_amdgcn_mfma_f32_16x16x32_bf16(
                pf[fm], vf[fn], acc[fm][fn], 0, 0, 0);
      }
    }
  }

  const int b = bh >> 4;
  const int h = bh & 15;
#pragma unroll
  for (int fm = 0; fm < 2; ++fm) {
    float inv = 1.0f / lrun[fm];
    float ivr[4];
#pragma unroll
    for (int r = 0; r < 4; ++r) ivr[r] = __shfl(inv, lh * 4 + r);
#pragma unroll
    for (int r = 0; r < 4; ++r) {
      int s = qrow + fm * 16 + lh * 4 + r;
#pragma unroll
      for (int fn = 0; fn < 4; ++fn) {
        int dh = fn * 16 + l15;
        Cg[((size_t)(b * SEQ + s)) * D_MODEL + h * HDIM + dh] =
            f2bf(acc[fm][fn][r] * ivr[r]);
      }
    }
  }
}

// ---------------------------------------------------------------- launch
extern "C" void kernel_launch(void* const* d_in, const int* in_sizes, int n_in,
                              void* d_out, int out_size, void* d_ws, size_t ws_size,
                              hipStream_t stream) {
  const float* x = (const float*)d_in[0];
  const float* Wq = (const float*)d_in[1];
  const float* Wk = (const float*)d_in[2];
  const float* Wv = (const float*)d_in[3];
  const float* Wo = (const float*)d_in[4];
  float* out = (float*)d_out;

  char* ws = (char*)d_ws;
  unsigned short* xb   = (unsigned short*)(ws);                    // 16 MB
  unsigned short* Wqkv = (unsigned short*)(ws + (16u << 20));      // 6 MB
  unsigned short* Wob  = (unsigned short*)(ws + (22u << 20));      // 2 MB
  unsigned short* Qb   = (unsigned short*)(ws + (24u << 20));      // 16 MB
  unsigned short* Kb   = (unsigned short*)(ws + (40u << 20));      // 16 MB
  unsigned short* Vtb  = (unsigned short*)(ws + (56u << 20));      // 16 MB (V^T)
  unsigned short* Cb   = (unsigned short*)(ws + (72u << 20));      // 16 MB

  const int W4 = (D_MODEL * D_MODEL) / 4;
  cvt_kernel<<<dim3(8192), dim3(256), 0, stream>>>(x, xb, (BATCH * SEQ * D_MODEL) / 4);
  cvt_kernel<<<dim3(1024), dim3(256), 0, stream>>>(Wq, Wqkv, W4);
  cvt_kernel<<<dim3(1024), dim3(256), 0, stream>>>(Wk, Wqkv + D_MODEL * D_MODEL, W4);
  cvt_kernel<<<dim3(1024), dim3(256), 0, stream>>>(Wv, Wqkv + 2 * D_MODEL * D_MODEL, W4);
  cvt_kernel<<<dim3(1024), dim3(256), 0, stream>>>(Wo, Wob, W4);

  gemm_bt<0><<<dim3(16, 64), dim3(256), 0, stream>>>(xb, Wqkv, Qb, Kb, nullptr, nullptr);
  gemm_bt<2><<<dim3(8, 64), dim3(256), 0, stream>>>(xb, Wqkv, nullptr, nullptr, Vtb, nullptr);
  attn_fwd<<<dim3(64, 16), dim3(256), 0, stream>>>(Qb, Kb, Vtb, Cb);
  gemm_bt<1><<<dim3(8, 64), dim3(256), 0, stream>>>(Cb, Wob, nullptr, nullptr, nullptr, out);
}